// Round 10
// baseline (131.745 us; speedup 1.0000x reference)
//
#include <hip/hip_runtime.h>
#include <math.h>

#define ALPHA 8.3f
// Per superstep (32 ch): X = 4 planes x 288 slices (4 rows x 66 cols + 24 pad) = 1152 granules
// (PADDED so X-DMA = exactly 3 full wave-slots/thread -> no divergent global_load_lds:
//  the LDS dest is wave-uniform base + lane*16, divergent dests corrupt LDS [v13 bug]).
// W = 36 frags (9 taps x 2 mt x 2 kc) x 64 lanes = 2304 granules. Granule = 16 B.
#define XSZ   18432
#define WSZ   36864
#define BUFSZ 55296   // XSZ + WSZ; double-buffered -> 110,592 B LDS (gfx950: 160 KB/CU)

typedef short v8s  __attribute__((ext_vector_type(8)));
typedef float v16f __attribute__((ext_vector_type(16)));
typedef float v4f  __attribute__((ext_vector_type(4)));

static __device__ __forceinline__ unsigned short f2bf(float f) {
    unsigned int u = __float_as_uint(f);
    u = (u + 0x7fffu + ((u >> 16) & 1u)) >> 16;   // RNE
    return (unsigned short)u;
}

static __device__ __forceinline__ void async16(const void* g, void* l) {
    __builtin_amdgcn_global_load_lds(
        (const __attribute__((address_space(1))) unsigned int*)g,
        (__attribute__((address_space(3))) unsigned int*)l, 16, 0, 0);
}

// Merged prep + cast (unchanged from v12 -- correct).
// Blocks [0,4096): x fp32 NCHW -> bf16 NHWC (x2[b][h][w][c]).
// Blocks [4096,5248): weight pre-swizzle, v12 layout:
//   F = ((ss*9 + tap)*2 + mt)*2 + kc; wt[F*512 + lane*8 + j];
//   o = mt*32+(lane&31), cin = ss*32 + kc*16 + (lane>>5)*8 + j.
// Block 4096 also zeroes the 1 KB halo buffer.
__global__ __launch_bounds__(256) void prep_and_cast(const float* __restrict__ x,
                                                     unsigned short* __restrict__ x2,
                                                     const float* __restrict__ w,
                                                     unsigned short* __restrict__ wt,
                                                     float* __restrict__ zb) {
    __shared__ float st[64][65];
    const int bx  = blockIdx.x;
    const int tid = threadIdx.x;
    if (bx >= 4096) {
        if (bx == 4096) zb[tid] = 0.f;    // 256 floats = 1 KB
        const int i = (bx - 4096) * 256 + tid;   // 0..294911
        const int j    = i & 7;
        const int lane = (i >> 3) & 63;
        const int F    = i >> 9;          // 0..575
        const int kc   = F & 1;
        const int mt   = (F >> 1) & 1;
        const int tq   = F >> 2;          // 0..143
        const int tap  = tq % 9;
        const int ss   = tq / 9;
        const int o    = mt * 32 + (lane & 31);
        const int cin  = ss * 32 + kc * 16 + (lane >> 5) * 8 + j;
        wt[i] = f2bf(w[(o * 512 + cin) * 9 + tap]);
        return;
    }
    const int cq = bx & 7;            // 64-ch eighth
    const int h  = (bx >> 3) & 63;
    const int b  = bx >> 9;
    const float* xb = x + ((size_t)b * 512 + cq * 64) * 4096 + h * 64;
    unsigned short* ob = x2 + (((size_t)b * 64 + h) * 64) * 512 + cq * 64;
#pragma unroll
    for (int i = 0; i < 4; ++i) {
        const int c  = i * 16 + (tid >> 4);
        const int w4 = (tid & 15) * 4;
        const float4 v = *(const float4*)&xb[(size_t)c * 4096 + w4];
        st[c][w4]     = v.x;
        st[c][w4 + 1] = v.y;
        st[c][w4 + 2] = v.z;
        st[c][w4 + 3] = v.w;
    }
    __syncthreads();
#pragma unroll
    for (int j = 0; j < 2; ++j) {
        const int idx = j * 256 + tid;
        const int ww = idx >> 3, k = idx & 7;
        unsigned short t[8];
#pragma unroll
        for (int e = 0; e < 8; ++e) t[e] = f2bf(st[k * 8 + e][ww]);
        uint4 u;
        u.x = t[0] | ((unsigned)t[1] << 16);
        u.y = t[2] | ((unsigned)t[3] << 16);
        u.z = t[4] | ((unsigned)t[5] << 16);
        u.w = t[6] | ((unsigned)t[7] << 16);
        *(uint4*)&ob[(size_t)ww * 512 + k * 8] = u;
    }
}

// Main v14 = v12 compute + counted-vmcnt pipeline, X padded to 1152 granules so every
// thread issues EXACTLY 9 async16/phase with lane-linear LDS dests (zero divergence --
// the v13 corruption is structurally impossible). Schedule per phase:
//   ISSUE(ss+1) -> s_waitcnt vmcnt(9) -> s_barrier -> MFMA phase (setprio 1)
//   -> s_waitcnt lgkmcnt(0) -> s_barrier.
// DMA(ss+1)'s 9 loads stay in flight across both barriers (vmcnt never 0 in-loop).
// ds_read/MFMA/epilogue order identical to v12 -> bit-identical numerics.
__global__ __launch_bounds__(384, 2)
void depthconv_v14(const unsigned short* __restrict__ x2,
                   const float* __restrict__ depth,
                   const unsigned short* __restrict__ wt,
                   const float* __restrict__ zbuf,
                   float* __restrict__ out) {
    __shared__ __align__(16) char smem[2 * BUFSZ];   // 110,592 B (epilogue reuses)

    // XCD-swizzled decode: xcd owns row-tiles [xcd*4, xcd*4+4) for all b
    const int bx   = blockIdx.x;
    const int xcd  = bx & 7;
    const int i0   = bx >> 3;            // 0..31
    const int b    = i0 & 7;
    const int h0   = (xcd * 4 + (i0 >> 3)) * 2;   // 0..62, 2 rows per block

    const int tid  = threadIdx.x;
    const int wid  = tid >> 6;           // 0..5
    const int lane = tid & 63;
    const int l31  = lane & 31;
    const int half = lane >> 5;
    const int rt   = wid & 1;            // wave's row within the 2-row tile
    const int di   = wid >> 1;           // kernel row 0..2

    const char* xpix = (const char*)(x2 + ((size_t)b * 4096) * 512);

    // ---- X-DMA source pointers (ss-invariant; advance += 64 B per ss) ----
    // dest granule i (0..1151): plane g = i/288 (8-ch plane 0..3), s = i%288;
    // s < 264: slice r*66+c -> pixel (h0-1+r, c-1), src = pix*1024 + ss*64 + g*16;
    // s >= 264 or OOB: zbuf (dummy/halo; staged bytes never read by compute).
    // zbuf advance 15*64+16 = 976 <= 1024 B, safe.
    const char* p0; const char* p1; const char* p2;
#define MKPTR(P, I)                                                              \
    {                                                                            \
        const int g_ = (I) / 288;                                                \
        const int s_ = (I) - g_ * 288;                                           \
        const int r_ = s_ / 66, c_ = s_ - r_ * 66;                               \
        const int hh = h0 - 1 + r_, ww = c_ - 1;                                 \
        P = (s_ < 264 && hh >= 0 && hh < 64 && ww >= 0 && ww < 64)               \
                ? xpix + (size_t)(hh * 64 + ww) * 1024 + g_ * 16                 \
                : (const char*)zbuf;                                             \
    }
    MKPTR(p0, tid)
    MKPTR(p1, 384 + tid)
    MKPTR(p2, 768 + tid)
    const char* wsrc = (const char*)wt;   // advances += WSZ per ss

    // Every thread issues EXACTLY 9 async16 per ISSUE (6 W + 3 X) -> vmcnt(9) exact.
#define ISSUE(BSEL)                                                              \
    {                                                                            \
        char* dst = smem + (BSEL) * BUFSZ;                                       \
        _Pragma("unroll")                                                        \
        for (int k = 0; k < 6; ++k)                                              \
            async16(wsrc + (size_t)(k * 384 + tid) * 16,                         \
                    dst + XSZ + (k * 384 + tid) * 16);                           \
        async16(p0, dst + tid * 16);                                             \
        async16(p1, dst + (384 + tid) * 16);                                     \
        async16(p2, dst + (768 + tid) * 16);                                     \
        p0 += 64; p1 += 64; p2 += 64; wsrc += WSZ;                               \
    }

    // ---- gates gt[n][dj] (depth loads complete BEFORE the counted pipeline) ----
    float gt[2][3];
    {
        const float* dp = depth + (size_t)b * 4096;
        const int hq = h0 + rt;
        const int hn = hq + di - 1;
#pragma unroll
        for (int n = 0; n < 2; ++n) {
            const int wq = n * 32 + l31;
            const float d0 = dp[hq * 64 + wq];
#pragma unroll
            for (int dj = 0; dj < 3; ++dj) {
                const int wn = wq + dj - 1;
                const float dn = (hn >= 0 && hn < 64 && wn >= 0 && wn < 64)
                                     ? dp[hn * 64 + wn] : 0.f;
                gt[n][dj] = __expf(-ALPHA * fabsf(d0 - dn));
            }
        }
    }
#pragma unroll
    for (int n = 0; n < 2; ++n)
#pragma unroll
        for (int dj = 0; dj < 3; ++dj) asm volatile("" : "+v"(gt[n][dj]));
    asm volatile("s_waitcnt vmcnt(0)" ::: "memory");   // depth loads out of the count

    ISSUE(0);

    v16f a00[3], a01[3], a10[3], a11[3];   // acc[dj][n][mt]: aNM, N=n, M=mt
#pragma unroll
    for (int d = 0; d < 3; ++d)
#pragma unroll
        for (int r = 0; r < 16; ++r) { a00[d][r] = 0.f; a01[d][r] = 0.f;
                                       a10[d][r] = 0.f; a11[d][r] = 0.f; }

    // per-thread LDS addr bases (buffer offset added per ss)
    const int aOff = XSZ + di * 12288 + lane * 16;              // + ((dj*2+mt)*2+kc)*1024
    // B plane = kc*2+half, stride 288 granules (4608 B); kc stride 9216 B.
    const int bOff = (half * 288 + (rt + di) * 66 + l31) * 16;  // + kc*9216 + (n*32+dj)*16

    for (int ss = 0; ss < 16; ++ss) {
        const int cur = ss & 1;
        if (ss < 15) {
            ISSUE(cur ^ 1);                               // DMA(ss+1): stays in flight
            asm volatile("s_waitcnt vmcnt(9)" ::: "memory");   // DMA(ss) landed
        } else {
            asm volatile("s_waitcnt vmcnt(0)" ::: "memory");
        }
        __builtin_amdgcn_s_barrier();                     // all waves' DMA(ss) landed
        __builtin_amdgcn_sched_barrier(0);
        const char* ba = smem + cur * BUFSZ + aOff;
        const char* bb = smem + cur * BUFSZ + bOff;
        __builtin_amdgcn_s_setprio(1);
#pragma unroll
        for (int dj = 0; dj < 3; ++dj) {
#pragma unroll
            for (int kc = 0; kc < 2; ++kc) {
                const v8s w0 = *(const v8s*)(ba + ((dj * 2 + 0) * 2 + kc) * 1024);
                const v8s w1 = *(const v8s*)(ba + ((dj * 2 + 1) * 2 + kc) * 1024);
                const v8s x0 = *(const v8s*)(bb + kc * 9216 + (0 * 32 + dj) * 16);
                const v8s x1 = *(const v8s*)(bb + kc * 9216 + (1 * 32 + dj) * 16);
                a00[dj] = __builtin_amdgcn_mfma_f32_32x32x16_bf16(w0, x0, a00[dj], 0, 0, 0);
                a01[dj] = __builtin_amdgcn_mfma_f32_32x32x16_bf16(w1, x0, a01[dj], 0, 0, 0);
                a10[dj] = __builtin_amdgcn_mfma_f32_32x32x16_bf16(w0, x1, a10[dj], 0, 0, 0);
                a11[dj] = __builtin_amdgcn_mfma_f32_32x32x16_bf16(w1, x1, a11[dj], 0, 0, 0);
            }
        }
        __builtin_amdgcn_s_setprio(0);
        asm volatile("s_waitcnt lgkmcnt(0)" ::: "memory");   // my ds_reads done
        __builtin_amdgcn_s_barrier();                        // buf[cur] safe to overwrite
        __builtin_amdgcn_sched_barrier(0);
    }

    // ---- epilogue: gate-combine per tap into [0] slot (in place) ----
#pragma unroll
    for (int r = 0; r < 16; ++r) {
        a00[0][r] = gt[0][0] * a00[0][r];
        a00[0][r] = fmaf(gt[0][1], a00[1][r], a00[0][r]);
        a00[0][r] = fmaf(gt[0][2], a00[2][r], a00[0][r]);
        a01[0][r] = gt[0][0] * a01[0][r];
        a01[0][r] = fmaf(gt[0][1], a01[1][r], a01[0][r]);
        a01[0][r] = fmaf(gt[0][2], a01[2][r], a01[0][r]);
        a10[0][r] = gt[1][0] * a10[0][r];
        a10[0][r] = fmaf(gt[1][1], a10[1][r], a10[0][r]);
        a10[0][r] = fmaf(gt[1][2], a10[2][r], a10[0][r]);
        a11[0][r] = gt[1][0] * a11[0][r];
        a11[0][r] = fmaf(gt[1][1], a11[1][r], a11[0][r]);
        a11[0][r] = fmaf(gt[1][2], a11[2][r], a11[0][r]);
    }

    // ---- di-reduction in LDS (RMW, 2 x 16 KB regions, qd-major = conflict-free) ----
    __syncthreads();
    float* red = (float*)smem;
    const int rbase = rt * 4096 + lane * 4;
#define EPI_STORE(ACC, N, MT)                                                    \
    _Pragma("unroll")                                                            \
    for (int qd = 0; qd < 4; ++qd) {                                             \
        v4f v; v[0] = ACC[0][qd * 4]; v[1] = ACC[0][qd * 4 + 1];                 \
        v[2] = ACC[0][qd * 4 + 2]; v[3] = ACC[0][qd * 4 + 3];                    \
        *(v4f*)&red[rbase + ((N) * 2 + (MT)) * 1024 + qd * 256] = v;             \
    }
#define EPI_ADD(ACC, N, MT)                                                      \
    _Pragma("unroll")                                                            \
    for (int qd = 0; qd < 4; ++qd) {                                             \
        v4f v = *(const v4f*)&red[rbase + ((N) * 2 + (MT)) * 1024 + qd * 256];   \
        v[0] += ACC[0][qd * 4];     v[1] += ACC[0][qd * 4 + 1];                  \
        v[2] += ACC[0][qd * 4 + 2]; v[3] += ACC[0][qd * 4 + 3];                  \
        *(v4f*)&red[rbase + ((N) * 2 + (MT)) * 1024 + qd * 256] = v;             \
    }
    if (di == 2) {
        EPI_STORE(a00, 0, 0) EPI_STORE(a01, 0, 1) EPI_STORE(a10, 1, 0) EPI_STORE(a11, 1, 1)
    }
    __syncthreads();
    if (di == 1) {
        EPI_ADD(a00, 0, 0) EPI_ADD(a01, 0, 1) EPI_ADD(a10, 1, 0) EPI_ADD(a11, 1, 1)
    }
    __syncthreads();
    if (di == 0) {
        float* ob = out + (size_t)b * 262144 + (h0 + rt) * 64;
#define EPI_OUT(ACC, N, MT)                                                      \
    _Pragma("unroll")                                                            \
    for (int qd = 0; qd < 4; ++qd) {                                             \
        const v4f v = *(const v4f*)&red[rbase + ((N) * 2 + (MT)) * 1024 + qd * 256]; \
        _Pragma("unroll")                                                        \
        for (int j = 0; j < 4; ++j) {                                            \
            const int rg = qd * 4 + j;                                           \
            const int o = (MT) * 32 + (rg & 3) + 8 * (rg >> 2) + 4 * half;       \
            ob[(size_t)o * 4096 + (N) * 32 + l31] = ACC[0][rg] + v[j];           \
        }                                                                        \
    }
        EPI_OUT(a00, 0, 0) EPI_OUT(a01, 0, 1) EPI_OUT(a10, 1, 0) EPI_OUT(a11, 1, 1)
    }
}

extern "C" void kernel_launch(void* const* d_in, const int* in_sizes, int n_in,
                              void* d_out, int out_size, void* d_ws, size_t ws_size,
                              hipStream_t stream) {
    const float* x      = (const float*)d_in[0];
    const float* depth  = (const float*)d_in[1];
    const float* weight = (const float*)d_in[2];
    float* out = (float*)d_out;

    unsigned short* wtb = (unsigned short*)d_ws;                        // 589,824 B
    float* zbuf         = (float*)((char*)d_ws + 786432);               // 1 KB zeros (halo)
    unsigned short* x2  = (unsigned short*)((char*)d_ws + (1 << 20));   // 33.6 MB bf16 NHWC

    prep_and_cast<<<5248, 256, 0, stream>>>(x, x2, weight, wtb, zbuf);
    depthconv_v14<<<256, 384, 0, stream>>>(x2, depth, wtb, zbuf, out);
}